// Round 5
// baseline (956.532 us; speedup 1.0000x reference)
//
#include <hip/hip_runtime.h>

// MeshAttention gfx950 — round 9: round-8 resubmit with ALIGNED pT stride.
// (round-8 failed: pT[.][133] -> 532-B row stride broke ds_*_b128 16-B
//  alignment; 132 floats = 528 B = 33*16 restores it.)
// K-tile 128 -> attn written in 512-B row chunks; __launch_bounds__(512,2)
// gives VGPR headroom for real K/V prefetch; validf computed in-kernel.
// B=4, H=8, E=1500, D=256, DK=DV=32, P+1=6, mask = dist<=3.

#define E_ 1500
#define D_ 256
#define HH 8
#define BB 4
#define MM (BB * E_)  // 6000
#define NKT_ 12       // K tiles of 128 -> 1536
#define PSTRIDE 132   // floats; 528 B = 33*16 -> b128-aligned, bank stride 4

typedef float f32x4 __attribute__((ext_vector_type(4)));
typedef short short8 __attribute__((ext_vector_type(8)));
typedef unsigned uint2v __attribute__((ext_vector_type(2)));

static __device__ inline unsigned short f2bf(float f) {
  unsigned u = __float_as_uint(f);
  unsigned r = (u + 0x7fff + ((u >> 16) & 1)) >> 16;
  return (unsigned short)r;
}
static __device__ inline float bf2f(unsigned short u) {
  return __uint_as_float(((unsigned)u) << 16);
}
static __device__ inline unsigned cvt_pk_bf16(float lo, float hi) {
  unsigned r;
  asm("v_cvt_pk_bf16_f32 %0, %1, %2" : "=v"(r) : "v"(lo), "v"(hi));
  return r;
}

// ------------------------------------------- transpose: x -> xt f32, xtb bf16
__global__ __launch_bounds__(256) void t0_transpose(const float* __restrict__ x,
                                                    float* __restrict__ xt,
                                                    unsigned short* __restrict__ xtb) {
  __shared__ float tl[32][33];
  const int b = blockIdx.z;
  const int dt = blockIdx.x * 32;
  const int et = blockIdx.y * 32;
  const int tx = threadIdx.x, ty = threadIdx.y;
#pragma unroll
  for (int j = 0; j < 4; j++) {
    int d = dt + ty + j * 8;
    int e = et + tx;
    float v = 0.f;
    if (e < E_) v = x[(size_t)b * D_ * E_ + (size_t)d * E_ + e];
    tl[ty + j * 8][tx] = v;
  }
  __syncthreads();
#pragma unroll
  for (int j = 0; j < 4; j++) {
    int e = et + ty + j * 8;
    int d = dt + tx;
    if (e < E_) {
      float v = tl[tx][ty + j * 8];
      size_t idx = ((size_t)b * E_ + e) * D_ + d;
      xt[idx] = v;
      xtb[idx] = f2bf(v);
    }
  }
}

// ------------------------------------------- weight convert+transpose -> bf16
__global__ __launch_bounds__(256) void t1_wt(const float* __restrict__ Wq,
                                             const float* __restrict__ Wk,
                                             const float* __restrict__ Wv,
                                             const float* __restrict__ Wfc,
                                             unsigned short* __restrict__ WT) {
  __shared__ float tl[32][33];
  const int mat = blockIdx.z;
  const float* W = (mat == 0) ? Wq : (mat == 1) ? Wk : (mat == 2) ? Wv : Wfc;
  const int kt = blockIdx.x * 32, nt = blockIdx.y * 32;
  const int tx = threadIdx.x, ty = threadIdx.y;
#pragma unroll
  for (int j = 0; j < 4; j++)
    tl[ty + j * 8][tx] = W[(size_t)(kt + ty + j * 8) * 256 + nt + tx];
  __syncthreads();
#pragma unroll
  for (int j = 0; j < 4; j++)
    WT[(size_t)mat * 65536 + (size_t)(nt + ty + j * 8) * 256 + kt + tx] =
        f2bf(tl[tx][ty + j * 8]);
}

// ---------------------------------------------------------------- layernorm
__global__ __launch_bounds__(256) void k1_ln(const float* __restrict__ xt,
                                             const float* __restrict__ lnw,
                                             const float* __restrict__ lnb,
                                             unsigned short* __restrict__ qnb) {
  const int m = blockIdx.x;
  const int t = threadIdx.x;
  float v = xt[(size_t)m * D_ + t];
  float s = v, s2 = v * v;
#pragma unroll
  for (int o = 1; o < 64; o <<= 1) {
    s += __shfl_xor(s, o);
    s2 += __shfl_xor(s2, o);
  }
  __shared__ float ps[4], ps2[4], mv[2];
  const int w = t >> 6;
  if ((t & 63) == 0) { ps[w] = s; ps2[w] = s2; }
  __syncthreads();
  if (t == 0) {
    float ts = ps[0] + ps[1] + ps[2] + ps[3];
    float ts2 = ps2[0] + ps2[1] + ps2[2] + ps2[3];
    float mu = ts * (1.f / 256.f);
    float var = ts2 * (1.f / 256.f) - mu * mu;
    mv[0] = mu;
    mv[1] = rsqrtf(var + 1e-6f);
  }
  __syncthreads();
  qnb[(size_t)m * D_ + t] = f2bf((v - mv[0]) * mv[1] * lnw[t] + lnb[t]);
}

// ------------------------------------------------- projections, LDS-free mfma
// mat 0=q (scaled, row-major qb), 1=k (FRAGMENT layout kbF), 2=v (FRAGMENT vbF).
__global__ __launch_bounds__(256) void kproj(
    const unsigned short* __restrict__ xtb, const unsigned short* __restrict__ qnb,
    const unsigned short* __restrict__ WT, unsigned short* __restrict__ qb,
    unsigned short* __restrict__ kbF, unsigned short* __restrict__ vbF) {
  const int mat = blockIdx.y >> 2;
  const int n0 = (blockIdx.y & 3) * 64;
  const int m0 = blockIdx.x * 64;
  const int t = threadIdx.x;
  const int w = t >> 6, l = t & 63, quad = l >> 4, l15 = l & 15;
  const unsigned short* A = (mat == 0) ? qnb : xtb;
  const unsigned short* B = WT + (size_t)mat * 65536;
  const float scale = (mat == 0) ? 0.17677669529663687f : 1.0f;

  int mrow = m0 + w * 16 + l15;
  if (mrow > MM - 1) mrow = MM - 1;
  short8 af[8];
#pragma unroll
  for (int kc = 0; kc < 8; kc++)
    af[kc] = *(const short8*)(A + (size_t)mrow * 256 + kc * 32 + quad * 8);

#pragma unroll
  for (int ntile = 0; ntile < 4; ntile++) {
    const int n = n0 + ntile * 16 + l15;
    f32x4 acc = {0.f, 0.f, 0.f, 0.f};
#pragma unroll
    for (int kc = 0; kc < 8; kc++) {
      short8 bf = *(const short8*)(B + (size_t)n * 256 + kc * 32 + quad * 8);
      acc = __builtin_amdgcn_mfma_f32_16x16x32_bf16(af[kc], bf, acc, 0, 0, 0);
    }
    if (mat == 1) {
      const int h = n >> 5, d = n & 31;
#pragma unroll
      for (int r = 0; r < 4; r++) {
        int m = m0 + w * 16 + quad * 4 + r;
        if (m < MM) {
          int bb = m / E_;
          int e = m - bb * E_;
          size_t idx =
              ((((size_t)(bb * 8 + h) * 24 + (e >> 6)) * 4 + ((e >> 4) & 3)) * 64 +
               (d >> 3) * 16 + (e & 15)) * 8 + (d & 7);
          kbF[idx] = f2bf(acc[r]);
        }
      }
    } else if (mat == 2) {
      const int h = n >> 5, dv = n & 31;
      int m = m0 + w * 16 + quad * 4;
      if (m < MM) {  // 4-row run stays in one b (1500 % 4 == 0)
        int bb = m / E_;
        int e = m - bb * E_;
        size_t idx =
            (((((size_t)(bb * 8 + h) * 24 + (e >> 6)) * 2 + ((e >> 5) & 1)) * 2 +
              (dv >> 4)) * 64 + ((e >> 3) & 3) * 16 + (dv & 15)) * 8 + (e & 7);
        uint2v uv;
        uv.x = (unsigned)f2bf(acc[0]) | ((unsigned)f2bf(acc[1]) << 16);
        uv.y = (unsigned)f2bf(acc[2]) | ((unsigned)f2bf(acc[3]) << 16);
        *(uint2v*)(vbF + idx) = uv;
      }
    } else {
#pragma unroll
      for (int r = 0; r < 4; r++) {
        int m = m0 + w * 16 + quad * 4 + r;
        if (m < MM) qb[(size_t)m * 256 + n] = f2bf(acc[r] * scale);
      }
    }
  }
}

// ---------------------------------------------------------------- attention
// grid 376 = (b, 16-row qtile), 512 thr = 8 waves = 8 heads. K-tile 128.
__global__ __launch_bounds__(512, 2) void k2_attn(
    const unsigned short* __restrict__ qb, const unsigned short* __restrict__ kbF,
    const unsigned short* __restrict__ vbF, const int* __restrict__ dist,
    const float* __restrict__ rpr, float* __restrict__ attn,
    unsigned short* __restrict__ aob, float* __restrict__ asum,
    float* __restrict__ validf) {
  __shared__ __align__(16) unsigned char dist8[16][1544];  // 24.7 KB
  __shared__ __align__(16) float pT[8][16][PSTRIDE];       // 67.6 KB, per-wave
  __shared__ float colacc[1544];                           // 6.2 KB

  // XCD-bijective swizzle: 376 = 8*47
  const int id = blockIdx.x;
  const int sw = (id & 7) * 47 + (id >> 3);
  const int b = sw / 94;
  const int qt = sw - b * 94;
  const int q0 = qt * 16;
  const int t = threadIdx.x;
  const int w = t >> 6, l = t & 63, quad = l >> 4, l15 = l & 15;

  // ---- stage dist as u8 [16 q][1544 k] (pad rows/cols with 8 = masked)
  for (int idx = t; idx < 6000; idx += 512) {
    int row = idx / 375, c = idx - row * 375;
    int qg = q0 + row;
    unsigned v = 0x08080808u;
    if (qg < E_) {
      int4 d4 = *(const int4*)(dist + ((size_t)b * E_ + qg) * E_ + c * 4);
      v = (unsigned)(d4.x & 255) | ((unsigned)(d4.y & 255) << 8) |
          ((unsigned)(d4.z & 255) << 16) | ((unsigned)(d4.w & 255) << 24);
    }
    *(unsigned*)&dist8[row][c * 4] = v;
  }
  for (int idx = t; idx < 176; idx += 512) {
    int row = idx / 11, c = idx - row * 11;
    *(unsigned*)&dist8[row][1500 + c * 4] = 0x08080808u;
  }
  for (int idx = t; idx < 1544; idx += 512) colacc[idx] = 0.f;

  // ---- per-wave setup (head w, q column = q0 + l15)
  const int qg = q0 + l15;
  const int qc = (qg < E_) ? qg : (E_ - 1);
  const bool qok = qg < E_;
  const short8 aq =
      *(const short8*)(qb + ((size_t)(b * E_ + qc)) * 256 + w * 32 + quad * 8);

  float qd0 = 0, qd1 = 0, qd2 = 0, qd3 = 0;
#pragma unroll
  for (int j = 0; j < 8; j++) {
    float qj = bf2f((unsigned short)aq[j]);
    qd0 += qj * rpr[0 * 32 + quad * 8 + j];
    qd1 += qj * rpr[1 * 32 + quad * 8 + j];
    qd2 += qj * rpr[2 * 32 + quad * 8 + j];
    qd3 += qj * rpr[3 * 32 + quad * 8 + j];
  }
  qd0 += __shfl_xor(qd0, 16); qd0 += __shfl_xor(qd0, 32);
  qd1 += __shfl_xor(qd1, 16); qd1 += __shfl_xor(qd1, 32);
  qd2 += __shfl_xor(qd2, 16); qd2 += __shfl_xor(qd2, 32);
  qd3 += __shfl_xor(qd3, 16); qd3 += __shfl_xor(qd3, 32);

  const unsigned short* kfb = kbF + (size_t)(b * 8 + w) * 49152;
  const unsigned short* vfb = vbF + (size_t)(b * 8 + w) * 49152;

  __syncthreads();

  // ---- validf from the staged dist tile (one wave; dist-only, head-indep)
  if (w == 0) {
    for (int c = l; c < E_; c += 64) {
      int cnt = 0;
#pragma unroll
      for (int r = 0; r < 16; r++) cnt += (dist8[r][c] <= 3);
      atomicAdd(validf + b * E_ + c, 8.f * (float)cnt);
    }
  }

  auto loadK = [&](int kt, short8 (&kf)[8]) {
#pragma unroll
    for (int s = 0; s < 8; s++)
      kf[s] = *(const short8*)(kfb + (size_t)((kt * 8 + s) * 64 + l) * 8);
  };

  f32x4 accOT0 = {0.f, 0.f, 0.f, 0.f}, accOT1 = {0.f, 0.f, 0.f, 0.f};
  float rs = 0.f;
  const int permLo = (((quad & 1) * 2) * 16 + l15) * 4;
  const int permHi = permLo + 64;
  const bool hiq = quad >= 2;

  // ================= sweep 1: S^T -> exp -> rs + O^T (no barriers) ==========
  auto body1 = [&](int kt, short8 (&kf)[8], short8 (&kn)[8], bool pf) {
    short8 vf[8];
#pragma unroll
    for (int kc = 0; kc < 4; kc++) {
      vf[kc * 2 + 0] =
          *(const short8*)(vfb + (size_t)(((kt * 4 + kc) * 2 + 0) * 64 + l) * 8);
      vf[kc * 2 + 1] =
          *(const short8*)(vfb + (size_t)(((kt * 4 + kc) * 2 + 1) * 64 + l) * 8);
    }
    if (pf) loadK(kt + 1, kn);
    const int kl0 = kt * 128;
    f32x4 c[8];
#pragma unroll
    for (int s = 0; s < 8; s++) {
      f32x4 z = {0.f, 0.f, 0.f, 0.f};
      c[s] = __builtin_amdgcn_mfma_f32_16x16x32_bf16(kf[s], aq, z, 0, 0, 0);
    }
    float ev[8][4];
#pragma unroll
    for (int s = 0; s < 8; s++) {
      unsigned du = *(const unsigned*)&dist8[l15][kl0 + s * 16 + quad * 4];
#pragma unroll
      for (int r = 0; r < 4; r++) {
        int dd = (du >> (8 * r)) & 255;
        float qv = (dd & 1) ? ((dd & 2) ? qd3 : qd1) : ((dd & 2) ? qd2 : qd0);
        float e = 0.f;
        if (dd <= 3) e = __expf(c[s][r] + qv);
        ev[s][r] = e;
        rs += e;
      }
    }
#pragma unroll
    for (int kc = 0; kc < 4; kc++) {
      unsigned pk0 = cvt_pk_bf16(ev[2 * kc][0], ev[2 * kc][1]);
      unsigned pk1 = cvt_pk_bf16(ev[2 * kc][2], ev[2 * kc][3]);
      unsigned pk2 = cvt_pk_bf16(ev[2 * kc + 1][0], ev[2 * kc + 1][1]);
      unsigned pk3 = cvt_pk_bf16(ev[2 * kc + 1][2], ev[2 * kc + 1][3]);
      unsigned lo0 = __builtin_amdgcn_ds_bpermute(permLo, pk0);
      unsigned hi0 = __builtin_amdgcn_ds_bpermute(permLo, pk2);
      unsigned lo1 = __builtin_amdgcn_ds_bpermute(permLo, pk1);
      unsigned hi1 = __builtin_amdgcn_ds_bpermute(permLo, pk3);
      unsigned lo2 = __builtin_amdgcn_ds_bpermute(permHi, pk0);
      unsigned hi2 = __builtin_amdgcn_ds_bpermute(permHi, pk2);
      unsigned lo3 = __builtin_amdgcn_ds_bpermute(permHi, pk1);
      unsigned hi3 = __builtin_amdgcn_ds_bpermute(permHi, pk3);
      union { unsigned u[4]; short8 s; } uu;
      uu.u[0] = hiq ? hi0 : lo0;
      uu.u[1] = hiq ? hi1 : lo1;
      uu.u[2] = hiq ? hi2 : lo2;
      uu.u[3] = hiq ? hi3 : lo3;
      accOT0 = __builtin_amdgcn_mfma_f32_16x16x32_bf16(vf[kc * 2 + 0], uu.s,
                                                       accOT0, 0, 0, 0);
      accOT1 = __builtin_amdgcn_mfma_f32_16x16x32_bf16(vf[kc * 2 + 1], uu.s,
                                                       accOT1, 0, 0, 0);
    }
  };

  short8 kA[8], kB[8];
  loadK(0, kA);
  for (int kt = 0; kt < NKT_; kt += 2) {
    body1(kt, kA, kB, true);
    body1(kt + 1, kB, kA, kt + 2 < NKT_);
  }

  rs += __shfl_xor(rs, 16);
  rs += __shfl_xor(rs, 32);
  const float rinv = (rs > 0.f) ? 1.f / rs : 0.f;

  if (qok) {
    uint2v u0, u1;
    u0.x = cvt_pk_bf16(accOT0[0] * rinv, accOT0[1] * rinv);
    u0.y = cvt_pk_bf16(accOT0[2] * rinv, accOT0[3] * rinv);
    u1.x = cvt_pk_bf16(accOT1[0] * rinv, accOT1[1] * rinv);
    u1.y = cvt_pk_bf16(accOT1[2] * rinv, accOT1[3] * rinv);
    unsigned short* ap = aob + ((size_t)(b * E_ + qg)) * 256 + w * 32;
    *(uint2v*)(ap + 0 * 16 + quad * 4) = u0;
    *(uint2v*)(ap + 1 * 16 + quad * 4) = u1;
  }

  // ================= sweep 2: recompute -> attn (512-B chunks) + colsum =====
  const int rq = l >> 4;  // readback sub-row
  auto body2 = [&](int kt, short8 (&kf)[8], short8 (&kn)[8], bool pf) {
    if (pf) loadK(kt + 1, kn);
    const int kl0 = kt * 128;
    f32x4 c[8];
#pragma unroll
    for (int s = 0; s < 8; s++) {
      f32x4 z = {0.f, 0.f, 0.f, 0.f};
      c[s] = __builtin_amdgcn_mfma_f32_16x16x32_bf16(kf[s], aq, z, 0, 0, 0);
    }
#pragma unroll
    for (int s = 0; s < 8; s++) {
      unsigned du = *(const unsigned*)&dist8[l15][kl0 + s * 16 + quad * 4];
      f32x4 p;
#pragma unroll
      for (int r = 0; r < 4; r++) {
        int dd = (du >> (8 * r)) & 255;
        float qv = (dd & 1) ? ((dd & 2) ? qd3 : qd1) : ((dd & 2) ? qd2 : qd0);
        float e = 0.f;
        if (dd <= 3) e = __expf(c[s][r] + qv) * rinv;
        p[r] = e;
      }
      *(f32x4*)&pT[w][l15][s * 16 + quad * 4] = p;
      float s0 = p[0], s1 = p[1], s2 = p[2], s3 = p[3];
#pragma unroll
      for (int o = 1; o < 16; o <<= 1) {
        s0 += __shfl_xor(s0, o);
        s1 += __shfl_xor(s1, o);
        s2 += __shfl_xor(s2, o);
        s3 += __shfl_xor(s3, o);
      }
      if (l15 == 0) {
        int cb = kl0 + s * 16 + quad * 4;
        atomicAdd(&colacc[cb + 0], s0);
        atomicAdd(&colacc[cb + 1], s1);
        atomicAdd(&colacc[cb + 2], s2);
        atomicAdd(&colacc[cb + 3], s3);
      }
    }
    // readback (same wave -> LDS ordered): 512-B contiguous runs per row
#pragma unroll
    for (int rg = 0; rg < 4; rg++) {
      const int r = rg * 4 + rq;
      const int qgr = q0 + r;
      if (qgr < E_) {
        const size_t rb = ((size_t)(b * 8 + w) * E_ + qgr) * E_ + kl0;
#pragma unroll
        for (int i = 0; i < 2; i++) {
          const int col = l15 * 4 + i * 64;
          const int kcol = kl0 + col;
          if (kcol < E_)
            *(float4*)(attn + rb + col) = *(const float4*)&pT[w][r][col];
        }
      }
    }
  };

  loadK(0, kA);
  for (int kt = 0; kt < NKT_; kt += 2) {
    body2(kt, kA, kB, true);
    body2(kt + 1, kB, kA, kt + 2 < NKT_);
  }

  __syncthreads();
  for (int idx = t; idx < E_; idx += 512)
    atomicAdd(asum + b * E_ + idx, colacc[idx]);
}

// ------------------------------------------- FC + residual, LDS transpose out
__global__ __launch_bounds__(256) void k_fc(const unsigned short* __restrict__ aob,
                                            const unsigned short* __restrict__ WT,
                                            const float* __restrict__ x,
                                            float* __restrict__ xout) {
  __shared__ float tl[64][65];
  const int n0 = blockIdx.y * 64;
  const int m0 = blockIdx.x * 64;
  const int t = threadIdx.x;
  const int w = t >> 6, l = t & 63, quad = l >> 4, l15 = l & 15;
  const unsigned short* B = WT + (size_t)3 * 65536;

  int mrow = m0 + w * 16 + l15;
  if (mrow > MM - 1) mrow = MM - 1;
  short8 af[8];
#pragma unroll
  for (int kc = 0; kc < 8; kc++)
    af[kc] = *(const short8*)(aob + (size_t)mrow * 256 + kc * 32 + quad * 8);

#pragma unroll
  for (int ntile = 0; ntile < 4; ntile++) {
    const int nl = ntile * 16 + l15;
    f32x4 acc = {0.f, 0.f, 0.f, 0.f};
#pragma unroll
    for (int kc = 0; kc < 8; kc++) {
      short8 bf = *(const short8*)(B + (size_t)(n0 + nl) * 256 + kc * 32 + quad * 8);
      acc = __builtin_amdgcn_mfma_f32_16x16x32_bf16(af[kc], bf, acc, 0, 0, 0);
    }
    const int ml = w * 16 + quad * 4;
#pragma unroll
    for (int r = 0; r < 4; r++) tl[ml + r][nl] = acc[r];
  }
  __syncthreads();
  const int nl = t >> 2;
  const int e0l = (t & 3) * 16;
  const int nc = n0 + nl;
#pragma unroll
  for (int i = 0; i < 4; i++) {
    int m = m0 + e0l + i * 4;
    if (m < MM) {
      int bb = m / E_;
      int e = m - bb * E_;
      size_t idx = ((size_t)bb * 256 + nc) * E_ + e;
      float4 rx = *(const float4*)(x + idx);
      float4 v = make_float4(tl[e0l + i * 4 + 0][nl] + rx.x,
                             tl[e0l + i * 4 + 1][nl] + rx.y,
                             tl[e0l + i * 4 + 2][nl] + rx.z,
                             tl[e0l + i * 4 + 3][nl] + rx.w);
      *(float4*)(xout + idx) = v;
    }
  }
}

__global__ __launch_bounds__(256) void k5_div(const float* __restrict__ asum,
                                              const float* __restrict__ validf,
                                              float* __restrict__ ape) {
  int i = blockIdx.x * 256 + threadIdx.x;
  if (i < BB * E_) ape[i] = asum[i] / validf[i];
}

// ---------------------------------------------------------------- launcher
extern "C" void kernel_launch(void* const* d_in, const int* in_sizes, int n_in,
                              void* d_out, int out_size, void* d_ws,
                              size_t ws_size, hipStream_t stream) {
  const float* x = (const float*)d_in[0];
  const int* dist = (const int*)d_in[1];
  const float* Wq = (const float*)d_in[2];
  const float* Wk = (const float*)d_in[3];
  const float* Wv = (const float*)d_in[4];
  const float* Wfc = (const float*)d_in[5];
  const float* lnw = (const float*)d_in[6];
  const float* lnb = (const float*)d_in[7];
  const float* rpr = (const float*)d_in[8];

  float* out0 = (float*)d_out;
  float* attn = out0 + 1536000;
  float* ape = out0 + 73536000;

  float* ws = (float*)d_ws;
  float* xt = ws;                                            // [6000,256] f32 (dead after k1_ln)
  unsigned short* kbF = (unsigned short*)ws;                 // aliases xt (written by kproj)
  unsigned short* xtb = (unsigned short*)(ws + 1536000);     // bf16 [6000,256]
  unsigned short* qnb = (unsigned short*)(ws + 2304000);     // bf16 [6000,256]
  unsigned short* qb = (unsigned short*)(ws + 3072000);      // bf16 [6000,256]
  unsigned short* vbF = (unsigned short*)(ws + 3840000);     // 1,572,864 shorts
  unsigned short* aob = (unsigned short*)(ws + 4626432);     // bf16 [6000,256]
  unsigned short* WT = (unsigned short*)(ws + 5394432);      // [4,256,256] bf16
  float* asum = ws + 5525504;                                // [6000]
  float* validf = ws + 5531504;                              // [6000]

  hipMemsetAsync(asum, 0, 12000 * sizeof(float), stream);
  hipMemsetAsync(vbF, 0, 1572864 * sizeof(unsigned short), stream);

  t0_transpose<<<dim3(8, 47, 4), dim3(32, 8), 0, stream>>>(x, xt, xtb);
  t1_wt<<<dim3(8, 8, 4), dim3(32, 8), 0, stream>>>(Wq, Wk, Wv, Wfc, WT);
  k1_ln<<<MM, 256, 0, stream>>>(xt, lnw, lnb, qnb);
  kproj<<<dim3(94, 12), 256, 0, stream>>>(xtb, qnb, WT, qb, kbF, vbF);
  k2_attn<<<376, 512, 0, stream>>>(qb, kbF, vbF, dist, rpr, attn, aob, asum,
                                   validf);
  k_fc<<<dim3(94, 4), 256, 0, stream>>>(aob, WT, x, out0);
  k5_div<<<24, 256, 0, stream>>>(asum, validf, ape);
}

// Round 6
// 585.685 us; speedup vs baseline: 1.6332x; 1.6332x over previous
//
#include <hip/hip_runtime.h>

// MeshAttention gfx950 — round 10: round-1 (proven 290us) attention kernel with
// surgical fixes of its MEASURED defects:
//  (a) V pre-transposed in GLOBAL (vbt [b,h,dv][1536]) by kproj -> vT staging is
//      clean b128 writes (kills the 32x ds_write_b16 transpose + bank conflicts)
//  (b) dist nibble-packed whole-range in LDS [32][772+pad], staged ONCE ->
//      sweep2 is barrier-free, dist HBM traffic halved
//  (c) rowsum/rinv in registers (no rowl atomics, no extra barriers)
//  (d) one barrier per K-tile (was two)
//  (e) t0+k1_ln fused (xt f32 eliminated)
// B=4, H=8, E=1500, D=256, DK=DV=32, P+1=6, mask = dist<=3.

#define E_ 1500
#define D_ 256
#define HH 8
#define BB 4
#define MM (BB * E_)  // 6000
#define NKT_ 24       // K tiles of 64 -> 1536
#define VROW 1536     // vbt row stride (shorts)

typedef float f32x4 __attribute__((ext_vector_type(4)));
typedef short short8 __attribute__((ext_vector_type(8)));
typedef unsigned uint2v __attribute__((ext_vector_type(2)));

static __device__ inline unsigned short f2bf(float f) {
  unsigned u = __float_as_uint(f);
  unsigned r = (u + 0x7fff + ((u >> 16) & 1)) >> 16;
  return (unsigned short)r;
}
static __device__ inline float bf2f(unsigned short u) {
  return __uint_as_float(((unsigned)u) << 16);
}

// ------------------------------------ fused transpose + layernorm -> bf16
// grid (47, 4), 256 thr. Produces xtb (x^T bf16) and qnb (LN(x^T) bf16).
__global__ __launch_bounds__(256) void t0ln(const float* __restrict__ x,
                                            const float* __restrict__ lnw,
                                            const float* __restrict__ lnb,
                                            unsigned short* __restrict__ xtb,
                                            unsigned short* __restrict__ qnb) {
  __shared__ float tl[32][257];
  const int b = blockIdx.y;
  const int e0 = blockIdx.x * 32;
  const int t = threadIdx.x;
  const int tx = t & 31, ty8 = t >> 5;
#pragma unroll
  for (int dt = 0; dt < 8; dt++) {
#pragma unroll
    for (int j = 0; j < 4; j++) {
      int d = dt * 32 + ty8 * 4 + j;
      int e = e0 + tx;
      float v = (e < E_) ? x[((size_t)b * D_ + d) * E_ + e] : 0.f;
      tl[tx][d] = v;
    }
  }
  __syncthreads();
  const int er = t >> 3, seg = t & 7;
  float s = 0.f, s2 = 0.f;
#pragma unroll
  for (int j = 0; j < 32; j++) {
    float v = tl[er][seg + j * 8];
    s += v;
    s2 += v * v;
  }
  s += __shfl_xor(s, 1); s2 += __shfl_xor(s2, 1);
  s += __shfl_xor(s, 2); s2 += __shfl_xor(s2, 2);
  s += __shfl_xor(s, 4); s2 += __shfl_xor(s2, 4);
  float mu = s * (1.f / 256.f);
  float var = s2 * (1.f / 256.f) - mu * mu;
  float rsig = rsqrtf(var + 1e-6f);
  int eg = e0 + er;
  if (eg < E_) {
    size_t ro = ((size_t)b * E_ + eg) * 256;
#pragma unroll
    for (int g = 0; g < 4; g++) {
      int d0 = seg * 32 + g * 8;
      union { unsigned short u[8]; short8 v; } xs, qs8;
#pragma unroll
      for (int j = 0; j < 8; j++) {
        float v = tl[er][d0 + j];
        xs.u[j] = f2bf(v);
        qs8.u[j] = f2bf((v - mu) * rsig * lnw[d0 + j] + lnb[d0 + j]);
      }
      *(short8*)(xtb + ro + d0) = xs.v;
      *(short8*)(qnb + ro + d0) = qs8.v;
    }
  }
}

// ------------------------------------------- weight convert+transpose -> bf16
__global__ __launch_bounds__(256) void t1_wt(const float* __restrict__ Wq,
                                             const float* __restrict__ Wk,
                                             const float* __restrict__ Wv,
                                             const float* __restrict__ Wfc,
                                             unsigned short* __restrict__ WT) {
  __shared__ float tl[32][33];
  const int mat = blockIdx.z;
  const float* W = (mat == 0) ? Wq : (mat == 1) ? Wk : (mat == 2) ? Wv : Wfc;
  const int kt = blockIdx.x * 32, nt = blockIdx.y * 32;
  const int tx = threadIdx.x, ty = threadIdx.y;
#pragma unroll
  for (int j = 0; j < 4; j++)
    tl[ty + j * 8][tx] = W[(size_t)(kt + ty + j * 8) * 256 + nt + tx];
  __syncthreads();
#pragma unroll
  for (int j = 0; j < 4; j++)
    WT[(size_t)mat * 65536 + (size_t)(nt + ty + j * 8) * 256 + kt + tx] =
        f2bf(tl[tx][ty + j * 8]);
}

// ------------------------------------------------- projections, LDS-free mfma
// mat 0=q (scaled, row-major qb), 1=k (row-major kb), 2=v (TRANSPOSED vbt).
__global__ __launch_bounds__(256) void kproj(
    const unsigned short* __restrict__ xtb, const unsigned short* __restrict__ qnb,
    const unsigned short* __restrict__ WT, unsigned short* __restrict__ qb,
    unsigned short* __restrict__ kb, unsigned short* __restrict__ vbt) {
  const int mat = blockIdx.y >> 2;
  const int n0 = (blockIdx.y & 3) * 64;
  const int m0 = blockIdx.x * 64;
  const int t = threadIdx.x;
  const int w = t >> 6, l = t & 63, quad = l >> 4, l15 = l & 15;
  const unsigned short* A = (mat == 0) ? qnb : xtb;
  const unsigned short* B = WT + (size_t)mat * 65536;
  const float scale = (mat == 0) ? 0.17677669529663687f : 1.0f;

  int mrow = m0 + w * 16 + l15;
  if (mrow > MM - 1) mrow = MM - 1;
  short8 af[8];
#pragma unroll
  for (int kc = 0; kc < 8; kc++)
    af[kc] = *(const short8*)(A + (size_t)mrow * 256 + kc * 32 + quad * 8);

#pragma unroll
  for (int ntile = 0; ntile < 4; ntile++) {
    const int n = n0 + ntile * 16 + l15;
    f32x4 acc = {0.f, 0.f, 0.f, 0.f};
#pragma unroll
    for (int kc = 0; kc < 8; kc++) {
      short8 bf = *(const short8*)(B + (size_t)n * 256 + kc * 32 + quad * 8);
      acc = __builtin_amdgcn_mfma_f32_16x16x32_bf16(af[kc], bf, acc, 0, 0, 0);
    }
    if (mat == 2) {
      int m = m0 + w * 16 + quad * 4;
      if (m < MM) {  // 4 consecutive e, same b (1500 % 4 == 0)
        int bb = m / E_, e0 = m - bb * E_;
        uint2v uv;
        uv.x = (unsigned)f2bf(acc[0]) | ((unsigned)f2bf(acc[1]) << 16);
        uv.y = (unsigned)f2bf(acc[2]) | ((unsigned)f2bf(acc[3]) << 16);
        *(uint2v*)(vbt + (size_t)((bb * 8 + (n >> 5)) * 32 + (n & 31)) * VROW +
                   e0) = uv;
      }
    } else {
      unsigned short* dst = (mat == 0) ? qb : kb;
#pragma unroll
      for (int r = 0; r < 4; r++) {
        int m = m0 + w * 16 + quad * 4 + r;
        if (m < MM) dst[(size_t)m * 256 + n] = f2bf(acc[r] * scale);
      }
    }
  }
}

// ---------------------------------------------------------------- attention
// grid 188 = (b, 32-row qtile), 512 thr = 8 waves = 8 heads.
__global__ __launch_bounds__(512, 2) void k2_attn(
    const unsigned short* __restrict__ qb, const unsigned short* __restrict__ kb,
    const unsigned short* __restrict__ vbt, const int* __restrict__ dist,
    const float* __restrict__ rpr, float* __restrict__ attn,
    unsigned short* __restrict__ aob, float* __restrict__ asum,
    float* __restrict__ validf) {
  __shared__ __align__(16) unsigned short vT[2][8][32][72];  // 73728 B
  __shared__ __align__(16) unsigned short pS[8][2320];       // 37120 B
  __shared__ __align__(16) unsigned char distN[32][776];     // 24832 B (nibbles)
  __shared__ float qdrS[8][32][4];                           // 4096 B
  __shared__ float colacc[1544];                             // 6176 B

  const int blk = blockIdx.x;
  const int b = blk / 47;
  const int qt = blk % 47;
  const int q0 = qt * 32;
  const int t = threadIdx.x;
  const int w = t >> 6, l = t & 63, quad = l >> 4, l15 = l & 15;

  // ---- stage dist as NIBBLES [32 q][1552 k] (pad = 8 -> masked)
  for (int idx = t; idx < 32 * 188; idx += 512) {
    int row = idx / 188, wd = idx - row * 188;
    int qg = q0 + row;
    int k0 = wd * 8;
    unsigned word = 0x88888888u;
    if (qg < E_) {
      const int* dp = dist + ((size_t)b * E_ + qg) * E_ + k0;
      int4 a = *(const int4*)dp;
      word = (unsigned)(a.x & 15) | ((unsigned)(a.y & 15) << 4) |
             ((unsigned)(a.z & 15) << 8) | ((unsigned)(a.w & 15) << 12);
      if (k0 + 8 <= E_) {
        int4 c = *(const int4*)(dp + 4);
        word |= ((unsigned)(c.x & 15) << 16) | ((unsigned)(c.y & 15) << 20) |
                ((unsigned)(c.z & 15) << 24) | ((unsigned)(c.w & 15) << 28);
      } else {
        word |= 0x88880000u;  // k 1500..1503 masked
      }
    }
    *(unsigned*)&distN[row][wd * 4] = word;
  }
  for (int idx = t; idx < 32 * 6; idx += 512) {  // pad words 188..193
    int row = idx / 6, wd = 188 + idx - (idx / 6) * 6;
    *(unsigned*)&distN[row][wd * 4] = 0x88888888u;
  }
  for (int idx = t; idx < 1544; idx += 512) colacc[idx] = 0.f;

  // ---- q_dot_rpr -> qdrS (round-1 verbatim)
#pragma unroll
  for (int ii = 0; ii < 2; ii++) {
    int id = t + ii * 512;
    int h = id >> 7, rem = id & 127, q = rem >> 2, p = rem & 3;
    int qg = q0 + q;
    float s = 0.f;
    if (qg < E_) {
      const unsigned short* qp = qb + ((size_t)(b * E_ + qg)) * 256 + h * 32;
      for (int d = 0; d < 32; d++) s += bf2f(qp[d]) * rpr[p * 32 + d];
    }
    qdrS[h][q][p] = s;
  }

  // ---- Q fragments (lane l15 = q row, quad = d chunk)
  short8 aq[2];
#pragma unroll
  for (int qs = 0; qs < 2; qs++) {
    int qg = q0 + qs * 16 + l15;
    if (qg > E_ - 1) qg = E_ - 1;
    aq[qs] = *(const short8*)(qb + ((size_t)(b * E_ + qg)) * 256 + w * 32 + quad * 8);
  }

  const unsigned short* kbase = kb + (size_t)b * E_ * 256 + w * 32 + quad * 8;
  // V staging map: rr = t>>1 -> (h, dv); half = t&1 -> 32-col group
  const int vrr = t >> 1, vh = vrr >> 5, vdv = vrr & 31, vc0 = (t & 1) * 32;
  const unsigned short* vsrc = vbt + (size_t)((b * 8 + vh) * 32 + vdv) * VROW + vc0;

  auto loadK = [&](int kt, short8 (&kf)[4]) {
#pragma unroll
    for (int ks = 0; ks < 4; ks++) {
      int kg = kt * 64 + ks * 16 + l15;
      if (kg > E_ - 1) kg = E_ - 1;
      kf[ks] = *(const short8*)(kbase + (size_t)kg * 256);
    }
  };
  auto loadV = [&](int kt, uint4 (&vr)[4]) {
#pragma unroll
    for (int j = 0; j < 4; j++) vr[j] = *(const uint4*)(vsrc + kt * 64 + j * 8);
  };
  auto writeV = [&](int buf, const uint4 (&vr)[4]) {
    uint4* dst = (uint4*)&vT[buf][vh][vdv][vc0];
#pragma unroll
    for (int j = 0; j < 4; j++) dst[j] = vr[j];
  };

  short8 kA[4], kB[4];
  f32x4 accPV[2][2];
#pragma unroll
  for (int qs = 0; qs < 2; qs++)
#pragma unroll
    for (int dvh = 0; dvh < 2; dvh++) {
      f32x4 z = {0.f, 0.f, 0.f, 0.f};
      accPV[qs][dvh] = z;
    }
  float rs[2][4] = {{0.f, 0.f, 0.f, 0.f}, {0.f, 0.f, 0.f, 0.f}};

  // prologue: stage V(0), load K(0)
  {
    uint4 vr[4];
    loadV(0, vr);
    loadK(0, kA);
    writeV(0, vr);
  }
  __syncthreads();

  // ================= sweep 1: QK^T -> exp -> rowsum + PV ====================
  auto body1 = [&](int kt, short8 (&kf)[4], short8 (&kn)[4], int cur) {
    const int ktn = (kt + 1 < NKT_) ? kt + 1 : kt;
    uint4 vr[4];
    loadV(ktn, vr);   // V(t+1) -> regs (in flight across compute)
    loadK(ktn, kn);   // K(t+1) -> regs
    const int kl0 = kt * 64;
#pragma unroll
    for (int qs = 0; qs < 2; qs++) {
#pragma unroll
      for (int ks = 0; ks < 4; ks++) {
        f32x4 z = {0.f, 0.f, 0.f, 0.f};
        f32x4 c = __builtin_amdgcn_mfma_f32_16x16x32_bf16(aq[qs], kf[ks], z, 0, 0, 0);
        const int kcol = kl0 + ks * 16 + l15;
#pragma unroll
        for (int r = 0; r < 4; r++) {
          int ql = qs * 16 + quad * 4 + r;
          int dd = (distN[ql][kcol >> 1] >> ((kcol & 1) * 4)) & 15;
          float e = 0.f;
          if (dd <= 3) e = __expf(c[r] + qdrS[w][ql][dd & 3]);
          rs[qs][r] += e;
          pS[w][ql * 72 + ks * 16 + l15] = f2bf(e);
        }
      }
    }
    // PV: pS wave-private (same-wave LDS ordering; no barrier)
#pragma unroll
    for (int kc = 0; kc < 2; kc++) {
      short8 bv0 = *(const short8*)&vT[cur][w][l15][kc * 32 + quad * 8];
      short8 bv1 = *(const short8*)&vT[cur][w][16 + l15][kc * 32 + quad * 8];
#pragma unroll
      for (int qs = 0; qs < 2; qs++) {
        short8 ap = *(const short8*)&pS[w][(qs * 16 + l15) * 72 + kc * 32 + quad * 8];
        accPV[qs][0] = __builtin_amdgcn_mfma_f32_16x16x32_bf16(ap, bv0, accPV[qs][0], 0, 0, 0);
        accPV[qs][1] = __builtin_amdgcn_mfma_f32_16x16x32_bf16(ap, bv1, accPV[qs][1], 0, 0, 0);
      }
    }
    writeV(cur ^ 1, vr);  // waits vmcnt for vr, then ds_write
    __syncthreads();      // one barrier per tile
  };

  for (int kt = 0; kt < NKT_; kt += 2) {
    body1(kt, kA, kB, 0);
    body1(kt + 1, kB, kA, 1);
  }

  // ---- rowsum -> rinv (registers; reduce over l15 = k direction)
  float rinv[2][4];
#pragma unroll
  for (int qs = 0; qs < 2; qs++)
#pragma unroll
    for (int r = 0; r < 4; r++) {
      float v = rs[qs][r];
      v += __shfl_xor(v, 1);
      v += __shfl_xor(v, 2);
      v += __shfl_xor(v, 4);
      v += __shfl_xor(v, 8);
      rinv[qs][r] = (v > 0.f) ? 1.f / v : 0.f;
    }

  // ---- ao = PV * rinv (bf16)
#pragma unroll
  for (int qs = 0; qs < 2; qs++)
#pragma unroll
    for (int dvh = 0; dvh < 2; dvh++) {
      f32x4 a = accPV[qs][dvh];
#pragma unroll
      for (int r = 0; r < 4; r++) {
        int ql = qs * 16 + quad * 4 + r;
        int qg = q0 + ql;
        if (qg < E_)
          aob[((size_t)(b * E_ + qg)) * 256 + w * 32 + dvh * 16 + l15] =
              f2bf(a[r] * rinv[qs][r]);
      }
    }

  // ---- validf from distN (dist-only; one wave)
  if (w == 0) {
    for (int c = l; c < E_; c += 64) {
      int cnt = 0;
#pragma unroll
      for (int r = 0; r < 32; r++)
        cnt += (((distN[r][c >> 1] >> ((c & 1) * 4)) & 15) <= 3);
      atomicAdd(validf + b * E_ + c, 8.f * (float)cnt);
    }
  }

  // ================= sweep 2: recompute -> attn + colsum (barrier-free) =====
  loadK(0, kA);
  auto body2 = [&](int kt, short8 (&kf)[4], short8 (&kn)[4]) {
    const int ktn = (kt + 1 < NKT_) ? kt + 1 : kt;
    loadK(ktn, kn);
    const int kl0 = kt * 64;
#pragma unroll
    for (int ks = 0; ks < 4; ks++) {
      const int kcol = kl0 + ks * 16 + l15;
      const bool kok = kcol < E_;
      float cs = 0.f;
#pragma unroll
      for (int qs = 0; qs < 2; qs++) {
        f32x4 z = {0.f, 0.f, 0.f, 0.f};
        f32x4 c = __builtin_amdgcn_mfma_f32_16x16x32_bf16(aq[qs], kf[ks], z, 0, 0, 0);
#pragma unroll
        for (int r = 0; r < 4; r++) {
          int ql = qs * 16 + quad * 4 + r;
          int dd = (distN[ql][kcol >> 1] >> ((kcol & 1) * 4)) & 15;
          float p = 0.f;
          if (dd <= 3) p = __expf(c[r] + qdrS[w][ql][dd & 3]) * rinv[qs][r];
          cs += p;
          int qg = q0 + ql;
          if (qg < E_ && kok)
            attn[((size_t)(b * 8 + w) * E_ + qg) * E_ + kcol] = p;
        }
      }
      cs += __shfl_xor(cs, 16);
      cs += __shfl_xor(cs, 32);
      if (quad == 0 && kok) atomicAdd(&colacc[kl0 + ks * 16 + l15], cs);
    }
  };

  for (int kt = 0; kt < NKT_; kt += 2) {
    body2(kt, kA, kB);
    body2(kt + 1, kB, kA);
  }

  __syncthreads();
  for (int idx = t; idx < E_; idx += 512)
    atomicAdd(asum + b * E_ + idx, colacc[idx]);
}

// ------------------------------------------- FC + residual, LDS transpose out
__global__ __launch_bounds__(256) void k_fc(const unsigned short* __restrict__ aob,
                                            const unsigned short* __restrict__ WT,
                                            const float* __restrict__ x,
                                            float* __restrict__ xout) {
  __shared__ float tl[64][65];
  const int n0 = blockIdx.y * 64;
  const int m0 = blockIdx.x * 64;
  const int t = threadIdx.x;
  const int w = t >> 6, l = t & 63, quad = l >> 4, l15 = l & 15;
  const unsigned short* B = WT + (size_t)3 * 65536;

  int mrow = m0 + w * 16 + l15;
  if (mrow > MM - 1) mrow = MM - 1;
  short8 af[8];
#pragma unroll
  for (int kc = 0; kc < 8; kc++)
    af[kc] = *(const short8*)(aob + (size_t)mrow * 256 + kc * 32 + quad * 8);

#pragma unroll
  for (int ntile = 0; ntile < 4; ntile++) {
    const int nl = ntile * 16 + l15;
    f32x4 acc = {0.f, 0.f, 0.f, 0.f};
#pragma unroll
    for (int kc = 0; kc < 8; kc++) {
      short8 bf = *(const short8*)(B + (size_t)(n0 + nl) * 256 + kc * 32 + quad * 8);
      acc = __builtin_amdgcn_mfma_f32_16x16x32_bf16(af[kc], bf, acc, 0, 0, 0);
    }
    const int ml = w * 16 + quad * 4;
#pragma unroll
    for (int r = 0; r < 4; r++) tl[ml + r][nl] = acc[r];
  }
  __syncthreads();
  const int nl = t >> 2;
  const int e0l = (t & 3) * 16;
  const int nc = n0 + nl;
#pragma unroll
  for (int i = 0; i < 4; i++) {
    int m = m0 + e0l + i * 4;
    if (m < MM) {
      int bb = m / E_;
      int e = m - bb * E_;
      size_t idx = ((size_t)bb * 256 + nc) * E_ + e;
      float4 rx = *(const float4*)(x + idx);
      float4 v = make_float4(tl[e0l + i * 4 + 0][nl] + rx.x,
                             tl[e0l + i * 4 + 1][nl] + rx.y,
                             tl[e0l + i * 4 + 2][nl] + rx.z,
                             tl[e0l + i * 4 + 3][nl] + rx.w);
      *(float4*)(xout + idx) = v;
    }
  }
}

__global__ __launch_bounds__(256) void k5_div(const float* __restrict__ asum,
                                              const float* __restrict__ validf,
                                              float* __restrict__ ape) {
  int i = blockIdx.x * 256 + threadIdx.x;
  if (i < BB * E_) ape[i] = asum[i] / validf[i];
}

// ---------------------------------------------------------------- launcher
extern "C" void kernel_launch(void* const* d_in, const int* in_sizes, int n_in,
                              void* d_out, int out_size, void* d_ws,
                              size_t ws_size, hipStream_t stream) {
  const float* x = (const float*)d_in[0];
  const int* dist = (const int*)d_in[1];
  const float* Wq = (const float*)d_in[2];
  const float* Wk = (const float*)d_in[3];
  const float* Wv = (const float*)d_in[4];
  const float* Wfc = (const float*)d_in[5];
  const float* lnw = (const float*)d_in[6];
  const float* lnb = (const float*)d_in[7];
  const float* rpr = (const float*)d_in[8];

  float* out0 = (float*)d_out;
  float* attn = out0 + 1536000;
  float* ape = out0 + 73536000;

  float* ws = (float*)d_ws;
  unsigned short* xtb = (unsigned short*)ws;                 // [6000,256] bf16
  unsigned short* qnb = (unsigned short*)(ws + 768000);      // bf16
  unsigned short* qb = (unsigned short*)(ws + 1536000);      // bf16
  unsigned short* kb = (unsigned short*)(ws + 2304000);      // bf16
  unsigned short* vbt = (unsigned short*)(ws + 3072000);     // [1024][1536] bf16
  unsigned short* aob = (unsigned short*)(ws + 3858432);     // bf16 [6000,256]
  unsigned short* WT = (unsigned short*)(ws + 4626432);      // [4,256,256] bf16
  float* asum = ws + 4757504;                                // [6000]
  float* validf = ws + 4763504;                              // [6000]

  hipMemsetAsync(asum, 0, 12000 * sizeof(float), stream);
  hipMemsetAsync(vbt, 0, 1572864 * sizeof(unsigned short), stream);

  t0ln<<<dim3(47, 4), 256, 0, stream>>>(x, lnw, lnb, xtb, qnb);
  t1_wt<<<dim3(8, 8, 4), dim3(32, 8), 0, stream>>>(Wq, Wk, Wv, Wfc, WT);
  kproj<<<dim3(94, 12), 256, 0, stream>>>(xtb, qnb, WT, qb, kb, vbt);
  k2_attn<<<188, 512, 0, stream>>>(qb, kb, vbt, dist, rpr, attn, aob, asum,
                                   validf);
  k_fc<<<dim3(94, 4), 256, 0, stream>>>(aob, WT, x, out0);
  k5_div<<<24, 256, 0, stream>>>(asum, validf, ape);
}